// Round 1
// baseline (868.627 us; speedup 1.0000x reference)
//
#include <hip/hip_runtime.h>

// Problem constants (from reference setup_inputs)
constexpr int NUM_BLOCKS   = 1024;
constexpr int BLOCK_SIZE   = 128;
constexpr int NUM_KV_HEADS = 8;
constexpr int HEAD_DIM     = 128;
constexpr int NUM_TOKENS   = 16384;
constexpr int ROW_ELEMS    = NUM_KV_HEADS * HEAD_DIM;          // 1024 floats = 4 KiB per token row
constexpr long long CACHE_ELEMS =
    (long long)NUM_BLOCKS * BLOCK_SIZE * NUM_KV_HEADS * HEAD_DIM; // 134,217,728 floats
constexpr long long CACHE_F4 = CACHE_ELEMS / 4;                // 33,554,432 float4

// Kernel 1: stream the whole cache into d_out. float4 = 16 B/lane, coalesced.
__global__ __launch_bounds__(256) void copy_cache_kernel(
    const float4* __restrict__ src, float4* __restrict__ dst, long long n4) {
    long long i = (long long)blockIdx.x * blockDim.x + threadIdx.x;
    if (i < n4) dst[i] = src[i];
}

// Kernel 2: scatter token rows. One block per token; 256 threads x float4 = 4 KiB row.
// Row base = ((block_idx*128 + offset) * 1024 floats) -> 4 KiB aligned, coalesced.
__global__ __launch_bounds__(256) void scatter_tokens_kernel(
    const float4* __restrict__ inp,
    const int*    __restrict__ block_indices,
    const int*    __restrict__ block_offset,
    float4*       __restrict__ out) {
    const int token = blockIdx.x;
    const int bi = block_indices[token];   // uniform per block -> scalar load
    const int bo = block_offset[token];
    const long long dst_row = ((long long)bi * BLOCK_SIZE + bo) * (ROW_ELEMS / 4);
    const long long src_row = (long long)token * (ROW_ELEMS / 4);
    out[dst_row + threadIdx.x] = inp[src_row + threadIdx.x];
}

extern "C" void kernel_launch(void* const* d_in, const int* in_sizes, int n_in,
                              void* d_out, int out_size, void* d_ws, size_t ws_size,
                              hipStream_t stream) {
    const float* input         = (const float*)d_in[0];
    const float* cache         = (const float*)d_in[1];
    const int*   block_indices = (const int*)d_in[2];
    const int*   block_offset  = (const int*)d_in[3];
    float*       out           = (float*)d_out;

    // 1) Full cache copy: 33.5M float4 / 256 threads = 131072 blocks.
    {
        const int threads = 256;
        const long long blocks = (CACHE_F4 + threads - 1) / threads;
        copy_cache_kernel<<<(int)blocks, threads, 0, stream>>>(
            (const float4*)cache, (float4*)out, CACHE_F4);
    }

    // 2) Scatter: one block per token (same stream -> ordered after the copy).
    {
        scatter_tokens_kernel<<<NUM_TOKENS, 256, 0, stream>>>(
            (const float4*)input, block_indices, block_offset, (float4*)out);
    }
}